// Round 5
// baseline (84.657 us; speedup 1.0000x reference)
//
#include <hip/hip_runtime.h>

// Problem constants (match reference)
#define NCONF   8
#define NATOMS  10
#define NSTATES 4
#define NBASIS  24
#define HIDDEN  48
#define NPAIRC  90          // ordered pairs per conf: 10*9
#define NNEI    9           // pairs per center atom (and per destination atom)
#define NDIR    30          // NATOMS*3 second-derivative directions
#define CUTOFF  6.0f
#define ALPHA   1.5f
#define PI_F    3.14159265358979323846f

// Second-order forward-mode jets (v, dv, d2v) per (conf, direction).
// kin[c,s] = -0.5 * sum_{m,l} massrev[c,m] * d2 psi[c,s] / d cart[c,m,l]^2
// == reference's einsum('jmliml->jmi') contracted with massrev.
//
// R5: wave-local phase chain. 10 waves/block, wave a owns atom a. Pairs of
// atom a are at canonical indices p = a*9+k (reference _make_pairs order:
// i outer, j inner skipping i, so j = k<a ? k : k+1). All per-atom phases
// (pairs -> density -> hidden -> initpsi) communicate through LDS written
// and read by the SAME wave: DS ops complete in order within a wave, so only
// compiler fences are needed. ONE block barrier before the cross-atom final
// reduction (vs 5 in R4). cart/species/W1 read direct from global (L2-hot,
// coalesced); no LDS staging phase.

__device__ __forceinline__ void wave_fence() {
    __builtin_amdgcn_wave_barrier();          // compiler scheduling fence
    asm volatile("" ::: "memory");            // compiler memory-motion fence
}

__device__ __forceinline__ float fast_tanh(float x) {
    return 1.0f - 2.0f / (__expf(2.0f * x) + 1.0f);
}

__global__ __launch_bounds__(640) void jet_kernel(
    const float* __restrict__ cart,      // [NCONF*NATOMS*3]
    const int*   __restrict__ species,   // [NCONF*NATOMS]
    const float* __restrict__ massrev,   // [NCONF*NATOMS]
    const float* __restrict__ shifts,    // [npairs*3]
    const float* __restrict__ W1,        // [NBASIS*HIDDEN]
    const float* __restrict__ B1,        // [NTYPES*HIDDEN]
    const float* __restrict__ W2,        // [HIDDEN*NSTATES]
    const float* __restrict__ Emb,       // [NTYPES*NSTATES]
    float* __restrict__ ws)              // [NCONF*NDIR*NSTATES + NCONF*NSTATES]
{
    __shared__ float pJ[NATOMS][NNEI][9];    // dv,dg,dh | fv,fg,fh | rv,rg,rh
    __shared__ float denJ[NATOMS][NBASIS][3];
    __shared__ float hJ[NATOMS][HIDDEN][3];
    __shared__ float psJ[NATOMS][NSTATES][3];
    __shared__ float RJ[NATOMS][3];

    const int tid  = threadIdx.x;
    const int a    = tid >> 6;               // wave index == atom index
    const int lane = tid & 63;
    const int c    = blockIdx.x / NDIR;
    const int d    = blockIdx.x % NDIR;
    const int m    = d / 3, l = d % 3;
    const float kc = PI_F / CUTOFF;

    // early loads (latency hidden under phases 1-2)
    const int   spc  = species[c*NATOMS + a];
    const float mrev = massrev[c*NATOMS + m];

    // ---- phase 1 (wave-local): pair jets for atom a, lanes 0..8 ----
    if (lane < NNEI) {
        const int k  = lane;
        const int j  = (k < a) ? k : k + 1;          // canonical _make_pairs order
        const int pg = c*NPAIRC + a*NNEI + k;        // global pair index
        const float sg = (float)((j == m) - (a == m));   // d dvec[l] / d eps
        const float dv0 = cart[c*NATOMS*3 + j*3 + 0] + shifts[pg*3+0] - cart[c*NATOMS*3 + a*3 + 0];
        const float dv1 = cart[c*NATOMS*3 + j*3 + 1] + shifts[pg*3+1] - cart[c*NATOMS*3 + a*3 + 1];
        const float dv2 = cart[c*NATOMS*3 + j*3 + 2] + shifts[pg*3+2] - cart[c*NATOMS*3 + a*3 + 2];
        const float dvl = (l == 0) ? dv0 : (l == 1) ? dv1 : dv2;
        const float r2v = dv0*dv0 + dv1*dv1 + dv2*dv2;
        const float r2g = 2.f*dvl*sg;
        const float r2h = 2.f*sg*sg;
        // dist = sqrt(r2)
        const float dvv = __fsqrt_rn(r2v);
        const float inv = 0.5f / dvv;
        const float dg  = r2g * inv;
        const float dh  = r2h * inv - 0.25f * r2g * r2g / (r2v * dvv);
        // radial = sin(kc*dist)^3 on UNclamped dist
        const float u  = kc * dvv;
        const float su = __sinf(u), cu = __cosf(u);
        const float r1  = 3.f*su*su*cu*kc;
        const float r2d = kc*kc*(6.f*su*cu*cu - 3.f*su*su*su);
        // fcut on clamped dist
        float dcv, dcg, dch;
        if (dvv < CUTOFF) { dcv = dvv; dcg = dg; dch = dh; }
        else              { dcv = CUTOFF; dcg = 0.f; dch = 0.f; }
        const float uc = kc * dcv;
        const float fv = 0.5f*(__cosf(uc) + 1.f);
        const float f1 = -0.5f*kc*__sinf(uc);
        const float f2 = -0.5f*kc*kc*__cosf(uc);
        pJ[a][k][0] = dvv; pJ[a][k][1] = dg;      pJ[a][k][2] = dh;
        pJ[a][k][3] = fv;  pJ[a][k][4] = f1*dcg;  pJ[a][k][5] = f1*dch + f2*dcg*dcg;
        pJ[a][k][6] = su*su*su;
        pJ[a][k][7] = r1*dg;
        pJ[a][k][8] = r1*dh + r2d*dg*dg;
    }
    wave_fence();

    // ---- phase 2 (wave-local): density jets for atom a, lanes 0..23 ----
    if (lane < NBASIS) {
        const int b = lane;
        const float cb = (CUTOFF/23.0f) * (float)b;
        float s0 = 0.f, s1 = 0.f, s2 = 0.f;
        #pragma unroll
        for (int k = 0; k < NNEI; ++k) {
            const float dvv = pJ[a][k][0], dg = pJ[a][k][1], dh = pJ[a][k][2];
            const float fv  = pJ[a][k][3], fg = pJ[a][k][4], fh = pJ[a][k][5];
            const float t  = dvv - cb;
            const float ev = __expf(-ALPHA*t*t);
            const float e1 = -2.f*ALPHA*t*ev;
            const float e2 = (-2.f*ALPHA + 4.f*ALPHA*ALPHA*t*t)*ev;
            const float eg = e1*dg;
            const float eh = e1*dh + e2*dg*dg;
            s0 += ev*fv;
            s1 += ev*fg + eg*fv;
            s2 += ev*fh + 2.f*eg*fg + eh*fv;
        }
        denJ[a][b][0] = s0; denJ[a][b][1] = s1; denJ[a][b][2] = s2;
    }
    wave_fence();

    // ---- phase 3 (wave-local): hidden = tanh(density @ W1 + B1), lanes 0..47 ----
    if (lane < HIDDEN) {
        const int hd = lane;
        float v = B1[spc*HIDDEN + hd], g = 0.f, hh = 0.f;
        #pragma unroll
        for (int b = 0; b < NBASIS; ++b) {
            const float w = W1[b*HIDDEN + hd];       // coalesced, L2-hot
            v  += denJ[a][b][0]*w;
            g  += denJ[a][b][1]*w;
            hh += denJ[a][b][2]*w;
        }
        const float y  = fast_tanh(v);
        const float y1 = 1.f - y*y;
        hJ[a][hd][0] = y;
        hJ[a][hd][1] = y1*g;
        hJ[a][hd][2] = y1*hh - 2.f*y*y1*g*g;
    }
    wave_fence();

    // ---- phase 4 (wave-local): initpsi = h @ W2 + Emb, lanes 0..3 ----
    if (lane < NSTATES) {
        const int s = lane;
        float v = Emb[spc*NSTATES + s], g = 0.f, hh = 0.f;
        #pragma unroll
        for (int hd = 0; hd < HIDDEN; ++hd) {
            const float w = W2[hd*NSTATES + s];
            v  += hJ[a][hd][0]*w;
            g  += hJ[a][hd][1]*w;
            hh += hJ[a][hd][2]*w;
        }
        psJ[a][s][0] = v; psJ[a][s][1] = g; psJ[a][s][2] = hh;
    }

    // ---- the ONE block barrier: cross-atom data (pJ radial, psJ) ----
    __syncthreads();

    // ---- phase 5 (wave 0 only): dst-grouped radial sums, then final emit ----
    if (tid < NATOMS) {
        const int j = tid;
        float r0 = 0.f, r1 = 0.f, r2 = 0.f;
        #pragma unroll
        for (int i = 0; i < NATOMS; ++i) {
            if (i == j) continue;
            const int k = (j < i) ? j : j - 1;       // slot of pair (i,j) in i's list
            r0 += pJ[i][k][6]; r1 += pJ[i][k][7]; r2 += pJ[i][k][8];
        }
        RJ[j][0] = r0; RJ[j][1] = r1; RJ[j][2] = r2;
    }
    wave_fence();
    if (tid < NSTATES) {
        const int s = tid;
        float t = 0.f, g = 0.f, hh = 0.f;
        #pragma unroll
        for (int j = 0; j < NATOMS; ++j) {
            const float rv = RJ[j][0], rg = RJ[j][1], rh = RJ[j][2];
            const float iv = psJ[j][s][0], ig = psJ[j][s][1], ih = psJ[j][s][2];
            t  += iv*rv;
            g  += iv*rg + ig*rv;
            hh += iv*rh + 2.f*ig*rg + ih*rv;
        }
        float pv, ph;
        if (s == 0) { pv = t*t; ph = 2.f*(t*hh + g*g); }
        else        { pv = t;   ph = hh; }
        ws[(c*NDIR + d)*NSTATES + s] = mrev * ph;
        if (d == 0) ws[NCONF*NDIR*NSTATES + c*NSTATES + s] = pv;
    }
}

__global__ __launch_bounds__(64) void finish_kernel(
    const float* __restrict__ ws,
    const float* __restrict__ pot,
    const float* __restrict__ elevel,
    float* __restrict__ out)
{
    const int t = threadIdx.x;
    float val = 0.f;
    if (t < NCONF*NSTATES) {
        const int c = t / NSTATES, s = t % NSTATES;
        float kin = 0.f;
        #pragma unroll
        for (int d = 0; d < NDIR; ++d) kin += ws[(c*NDIR + d)*NSTATES + s];
        kin *= -0.5f;                                  // FACTOR_KIN with the minus sign
        const float psi    = ws[NCONF*NDIR*NSTATES + c*NSTATES + s];
        const float potene = pot[c] - pot[NCONF-1];
        const float vib    = (kin + psi*potene) / psi;
        const float e      = vib - elevel[s];
        val = e*e;
    }
    #pragma unroll
    for (int off = 32; off > 0; off >>= 1) val += __shfl_down(val, off, 64);
    if (t == 0) out[0] = val;
}

extern "C" void kernel_launch(void* const* d_in, const int* in_sizes, int n_in,
                              void* d_out, int out_size, void* d_ws, size_t ws_size,
                              hipStream_t stream) {
    // input order: eigen_weight, pot, cart, numatoms, species, massrev,
    //              atom_index, shifts, W1, B1, W2, Emb, elevel
    const float* pot     = (const float*)d_in[1];
    const float* cart    = (const float*)d_in[2];
    const int*   species = (const int*)  d_in[4];
    const float* massrev = (const float*)d_in[5];
    const float* shifts  = (const float*)d_in[7];
    const float* W1      = (const float*)d_in[8];
    const float* B1      = (const float*)d_in[9];
    const float* W2      = (const float*)d_in[10];
    const float* Emb     = (const float*)d_in[11];
    const float* elevel  = (const float*)d_in[12];

    float* ws = (float*)d_ws;   // 992 floats used

    jet_kernel<<<NCONF*NDIR, 640, 0, stream>>>(cart, species, massrev, shifts,
                                               W1, B1, W2, Emb, ws);
    finish_kernel<<<1, 64, 0, stream>>>(ws, pot, elevel, (float*)d_out);
}